// Round 4
// baseline (1838.854 us; speedup 1.0000x reference)
//
#include <hip/hip_runtime.h>
#include <hip/hip_bf16.h>
#include <stdint.h>

#define TN 4096      // tokens (B*S)
#define DI 4096      // input dim
#define DH 1376      // GLU hidden dim
#define DHP 1408     // padded hidden (22*64, 44*32)
#define DO 4096      // output dim
#define NE 8         // experts
#define NPAIR 8192   // TN * K

typedef unsigned short u16;
typedef __bf16 bf16x8 __attribute__((ext_vector_type(8)));
typedef float f32x4 __attribute__((ext_vector_type(4)));
typedef uint32_t u32x4 __attribute__((ext_vector_type(4)));

__device__ __forceinline__ uint32_t pack2bf(float a, float b) {
    union { float f; uint32_t u; } ua, ub;
    ua.f = a; ub.f = b;
    uint32_t lo = (ua.u + 0x7fffu + ((ua.u >> 16) & 1u)) >> 16;
    uint32_t hi = (ub.u + 0x7fffu + ((ub.u >> 16) & 1u)) >> 16;
    return lo | (hi << 16);
}
__device__ __forceinline__ u16 f2bf(float a) {
    union { float f; uint32_t u; } ua; ua.f = a;
    return (u16)((ua.u + 0x7fffu + ((ua.u >> 16) & 1u)) >> 16);
}
__device__ __forceinline__ void gload16(const void* g, void* l) {
    __builtin_amdgcn_global_load_lds(
        (const __attribute__((address_space(1))) void*)g,
        (__attribute__((address_space(3))) void*)l, 16, 0, 0);
}
#define VMCNT0() asm volatile("s_waitcnt vmcnt(0)" ::: "memory")

// ---------------- weight converters ----------------
__global__ __launch_bounds__(256) void k_cvt(const float* __restrict__ src,
                                             u16* __restrict__ dst, int n8)
{
    int i = blockIdx.x * 256 + threadIdx.x;
    if (i >= n8) return;
    const float4* s = (const float4*)(src + (size_t)i * 8);
    float4 a = s[0], b = s[1];
    u32x4 q = {pack2bf(a.x, a.y), pack2bf(a.z, a.w), pack2bf(b.x, b.y), pack2bf(b.z, b.w)};
    *(u32x4*)(dst + (size_t)i * 8) = q;
}

// wd [8][4096][1376] f32 -> wd16 [8][4096][1408] bf16 (pad cols zeroed)
__global__ __launch_bounds__(256) void k_cvt_wd(const float* __restrict__ src,
                                                u16* __restrict__ dst)
{
    int i = blockIdx.x * 256 + threadIdx.x;
    int row = i / 176, c8 = (i % 176) * 8;
    u32x4 q = {0u, 0u, 0u, 0u};
    if (c8 < DH) {
        const float4* s = (const float4*)(src + (size_t)row * DH + c8);
        float4 a = s[0], b = s[1];
        q = (u32x4){pack2bf(a.x, a.y), pack2bf(a.z, a.w), pack2bf(b.x, b.y), pack2bf(b.z, b.w)};
    }
    *(u32x4*)(dst + (size_t)row * DHP + c8) = q;
}

// ---------------- Kernel 1: gate (f64-accurate) + x -> bf16 ----------------
__global__ __launch_bounds__(256) void k_gate(
    const float* __restrict__ x, const float* __restrict__ gw,
    u16* __restrict__ x16, int* __restrict__ tke, float* __restrict__ tks,
    int* __restrict__ cnt, float* __restrict__ imp)
{
    int t = blockIdx.x, tid = threadIdx.x;
    const float* xr = x + (size_t)t * DI;
    double acc[NE];
#pragma unroll
    for (int e = 0; e < NE; ++e) acc[e] = 0.0;
#pragma unroll
    for (int j = 0; j < 4; ++j) {
        int i4 = (j * 256 + tid) * 4;
        float4 xv = *(const float4*)(xr + i4);
        uint2 p; p.x = pack2bf(xv.x, xv.y); p.y = pack2bf(xv.z, xv.w);
        *(uint2*)(x16 + (size_t)t * DI + i4) = p;
#pragma unroll
        for (int e = 0; e < NE; ++e) {
            float4 wv = *(const float4*)(gw + (size_t)e * DI + i4);
            acc[e] = fma((double)xv.x, (double)wv.x, acc[e]);
            acc[e] = fma((double)xv.y, (double)wv.y, acc[e]);
            acc[e] = fma((double)xv.z, (double)wv.z, acc[e]);
            acc[e] = fma((double)xv.w, (double)wv.w, acc[e]);
        }
    }
#pragma unroll
    for (int o = 32; o > 0; o >>= 1)
#pragma unroll
        for (int e = 0; e < NE; ++e) acc[e] += __shfl_down(acc[e], o, 64);
    __shared__ double lred[4][NE];
    if ((tid & 63) == 0)
#pragma unroll
        for (int e = 0; e < NE; ++e) lred[tid >> 6][e] = acc[e];
    __syncthreads();
    if (tid == 0) {
        double lg[NE];
#pragma unroll
        for (int e = 0; e < NE; ++e) lg[e] = lred[0][e] + lred[1][e] + lred[2][e] + lred[3][e];
        int e1 = 0;
        for (int e = 1; e < NE; ++e) if (lg[e] > lg[e1]) e1 = e;
        int e2 = -1;
        for (int e = 0; e < NE; ++e) { if (e == e1) continue; if (e2 < 0 || lg[e] > lg[e2]) e2 = e; }
        float d = (float)(lg[e2] - lg[e1]);
        float ed = expf(d);
        float s1 = 1.0f / (1.0f + ed);
        float s2 = ed / (1.0f + ed);
        tke[2 * t] = e1; tke[2 * t + 1] = e2;
        tks[2 * t] = s1; tks[2 * t + 1] = s2;
        atomicAdd(&cnt[e1], 1); atomicAdd(&cnt[e2], 1);
        unsafeAtomicAdd(&imp[e1], s1); unsafeAtomicAdd(&imp[e2], s2);
    }
}

// ---------------- Kernel 2: offsets + gate_loss ----------------
__global__ void k_finalize(const int* __restrict__ cnt, const float* __restrict__ imp,
                           int* __restrict__ off, float* __restrict__ loss_out)
{
    if (threadIdx.x == 0 && blockIdx.x == 0) {
        int o = 0;
        for (int e = 0; e < NE; ++e) { off[e] = o; o += cnt[e]; }
        float m1 = 0.f, m2 = 0.f;
        for (int e = 0; e < NE; ++e) { m1 += imp[e]; m2 += (float)cnt[e]; }
        m1 *= 0.125f; m2 *= 0.125f;
        float v1 = 0.f, v2 = 0.f;
        for (int e = 0; e < NE; ++e) {
            float d1 = imp[e] - m1, d2 = (float)cnt[e] - m2;
            v1 += d1 * d1; v2 += d2 * d2;
        }
        v1 /= 7.0f; v2 /= 7.0f;
        float cv1 = v1 / (m1 * m1 + 1e-10f);
        float cv2 = v2 / (m2 * m2 + 1e-10f);
        *loss_out = 0.01f * (cv1 + cv2);
    }
}

// ---------------- Kernel 3: scatter tokens ----------------
__global__ __launch_bounds__(256) void k_scatter(
    const int* __restrict__ tke, const float* __restrict__ tks,
    const int* __restrict__ off, int* __restrict__ fill,
    int* __restrict__ tok, float* __restrict__ sc)
{
    int t = blockIdx.x * 256 + threadIdx.x;
    if (t >= TN) return;
#pragma unroll
    for (int k = 0; k < 2; ++k) {
        int e = tke[2 * t + k];
        int pos = off[e] + atomicAdd(&fill[e], 1);
        tok[pos] = t; sc[pos] = tks[2 * t + k];
    }
}

// ---------------- Kernel 4: y init with score-weighted b_down ----------------
__global__ __launch_bounds__(256) void k_yinit(
    const int* __restrict__ tke, const float* __restrict__ tks,
    const float* __restrict__ bd, float* __restrict__ y)
{
    int t = blockIdx.x, tid = threadIdx.x;
    int e1 = tke[2 * t], e2 = tke[2 * t + 1];
    float s1 = tks[2 * t], s2 = tks[2 * t + 1];
    const float4* b1 = (const float4*)(bd + (size_t)e1 * DO);
    const float4* b2 = (const float4*)(bd + (size_t)e2 * DO);
    float4* yr = (float4*)(y + (size_t)t * DO);
#pragma unroll
    for (int j = 0; j < 4; ++j) {
        int i = j * 256 + tid;
        float4 a = b1[i], b = b2[i], r;
        r.x = s1 * a.x + s2 * b.x; r.y = s1 * a.y + s2 * b.y;
        r.z = s1 * a.z + s2 * b.z; r.w = s1 * a.w + s2 * b.w;
        yr[i] = r;
    }
}

// ============ pipelined bf16 GEMM kernels ============
// LDS tiles [128][32] bf16 (64B rows, 4 x 16B slots). Swizzle: phys slot
// p of row r holds logical col16-block (p ^ ((r>>1)&3)) -> reads are 2-way
// bank aliased (free). Rule 21: linear LDS dest (global_load_lds),
// inverse-swizzled GLOBAL source, same XOR on read.
// Pipeline: SEPARATE __shared__ objects per buffer (alias-free by
// construction, so the backend cannot inject a pre-MFMA vmcnt drain),
// static 2x-unrolled loop, raw s_barrier + explicit vmcnt(0) AFTER MFMA.

// ---------------- stage-1: fused GLU GEMM ----------------
__global__ __launch_bounds__(256, 3) void k_stage1d(
    const u16* __restrict__ x16,
    const u16* __restrict__ wg16, const u16* __restrict__ wu16,
    const float* __restrict__ bg, const float* __restrict__ bu,
    const int* __restrict__ cnt, const int* __restrict__ off,
    const int* __restrict__ tok, const float* __restrict__ sc,
    u16* __restrict__ inter)
{
    int e = blockIdx.x & 7;               // expert -> XCD affinity
    int ce = cnt[e];
    int rows0 = (blockIdx.x >> 3) * 128;
    if (rows0 >= ce) return;
    int oe = off[e];
    int h0 = blockIdx.y * 128;
    int tid = threadIdx.x;

    __shared__ u16 As0[128 * 32]; __shared__ u16 As1[128 * 32];
    __shared__ u16 Gs0[128 * 32]; __shared__ u16 Gs1[128 * 32];
    __shared__ u16 Us0[128 * 32]; __shared__ u16 Us1[128 * 32];

    // staging: thread t fills LDS rows (t>>2)+{0,64}, phys slot (t&3);
    // source logical col16-block = (t&3) ^ ((t>>3)&3)
    int swz = ((tid & 3) ^ ((tid >> 3) & 3)) * 8;
    const u16* ab0; const u16* ab1; const u16* gb0; const u16* gb1;
    const u16* ub0; const u16* ub1;
    {
        int rl0 = tid >> 2, rl1 = 64 + (tid >> 2);
        int rg0 = oe + min(rows0 + rl0, ce - 1);
        int rg1 = oe + min(rows0 + rl1, ce - 1);
        ab0 = x16 + (size_t)tok[rg0] * DI + swz;
        ab1 = x16 + (size_t)tok[rg1] * DI + swz;
        int hr0 = min(h0 + rl0, DH - 1), hr1 = min(h0 + rl1, DH - 1);
        gb0 = wg16 + ((size_t)e * DH + hr0) * DI + swz;
        gb1 = wg16 + ((size_t)e * DH + hr1) * DI + swz;
        ub0 = wu16 + ((size_t)e * DH + hr0) * DI + swz;
        ub1 = wu16 + ((size_t)e * DH + hr1) * DI + swz;
    }

    int wid = tid >> 6, lane = tid & 63;
    int wm = wid >> 1, wn = wid & 1;
    int rA = wm * 64 + (lane & 15);
    int rB = wn * 64 + (lane & 15);
    int colb = (((lane >> 4) ^ ((lane >> 1) & 3)) & 3) * 8;  // phys slot on read

    f32x4 accg[4][4], accu[4][4];
    f32x4 vz = {0.f, 0.f, 0.f, 0.f};
#pragma unroll
    for (int m = 0; m < 4; ++m)
#pragma unroll
        for (int n = 0; n < 4; ++n) { accg[m][n] = vz; accu[m][n] = vz; }

    int ldst = tid * 8;   // u16 elems; 16B per lane, wave-uniform base + lane*16

#define S1_STAGE(A_, G_, U_, K0)                                   \
    do {                                                           \
        gload16(ab0 + (K0), &A_[ldst]);                            \
        gload16(ab1 + (K0), &A_[2048 + ldst]);                     \
        gload16(gb0 + (K0), &G_[ldst]);                            \
        gload16(gb1 + (K0), &G_[2048 + ldst]);                     \
        gload16(ub0 + (K0), &U_[ldst]);                            \
        gload16(ub1 + (K0), &U_[2048 + ldst]);                     \
    } while (0)

#define S1_COMPUTE(A_, G_, U_)                                     \
    do {                                                           \
        bf16x8 a[4], g[4], u[4];                                   \
        _Pragma("unroll")                                          \
        for (int m = 0; m < 4; ++m)                                \
            a[m] = *(const bf16x8*)&A_[(rA + m * 16) * 32 + colb]; \
        _Pragma("unroll")                                          \
        for (int n = 0; n < 4; ++n) {                              \
            g[n] = *(const bf16x8*)&G_[(rB + n * 16) * 32 + colb]; \
            u[n] = *(const bf16x8*)&U_[(rB + n * 16) * 32 + colb]; \
        }                                                          \
        _Pragma("unroll")                                          \
        for (int m = 0; m < 4; ++m)                                \
            _Pragma("unroll")                                      \
            for (int n = 0; n < 4; ++n) {                          \
                accg[m][n] = __builtin_amdgcn_mfma_f32_16x16x32_bf16(a[m], g[n], accg[m][n], 0, 0, 0); \
                accu[m][n] = __builtin_amdgcn_mfma_f32_16x16x32_bf16(a[m], u[n], accu[m][n], 0, 0, 0); \
            }                                                      \
    } while (0)

    // prologue
    S1_STAGE(As0, Gs0, Us0, 0);
    VMCNT0();
    __builtin_amdgcn_s_barrier();

    const int NT = DI / 32;   // 128, even
    for (int kt = 0; kt < NT; kt += 2) {
        // even step: compute buf0, prefetch into buf1
        if (kt + 1 < NT) S1_STAGE(As1, Gs1, Us1, (kt + 1) * 32);
        S1_COMPUTE(As0, Gs0, Us0);
        VMCNT0();
        __builtin_amdgcn_s_barrier();
        // odd step: compute buf1, prefetch into buf0
        if (kt + 2 < NT) S1_STAGE(As0, Gs0, Us0, (kt + 2) * 32);
        S1_COMPUTE(As1, Gs1, Us1);
        VMCNT0();
        __builtin_amdgcn_s_barrier();
    }
#undef S1_STAGE
#undef S1_COMPUTE

    // epilogue: bias + silu + score-fold; zero-fill pad cols [DH, DHP)
    int rmax = ce - rows0;
    float bgv[4], buv[4];
    int hc[4]; bool hok[4];
#pragma unroll
    for (int n = 0; n < 4; ++n) {
        hc[n] = h0 + wn * 64 + n * 16 + (lane & 15);
        hok[n] = hc[n] < DH;
        bgv[n] = hok[n] ? bg[e * DH + hc[n]] : 0.f;
        buv[n] = hok[n] ? bu[e * DH + hc[n]] : 0.f;
    }
#pragma unroll
    for (int m = 0; m < 4; ++m) {
#pragma unroll
        for (int r = 0; r < 4; ++r) {
            int rl = wm * 64 + m * 16 + (lane >> 4) * 4 + r;
            if (rl < rmax) {
                int rg = oe + rows0 + rl;
                float s = sc[rg];
                size_t rowb = (size_t)rg * DHP;
#pragma unroll
                for (int n = 0; n < 4; ++n) {
                    float v = 0.f;
                    if (hok[n]) {
                        float gv = accg[m][n][r] + bgv[n];
                        float uv = accu[m][n][r] + buv[n];
                        float sig = 1.0f / (1.0f + __expf(-gv));
                        v = s * gv * sig * uv;
                    }
                    inter[rowb + hc[n]] = f2bf(v);
                }
            }
        }
    }
}

// ---------------- stage-2: down-proj GEMM + atomic scatter ----------------
__global__ __launch_bounds__(256, 4) void k_stage2d(
    const u16* __restrict__ inter, const u16* __restrict__ wd16,
    const int* __restrict__ cnt, const int* __restrict__ off,
    const int* __restrict__ tok, float* __restrict__ y)
{
    int e = blockIdx.x & 7;
    int ce = cnt[e];
    int rows0 = (blockIdx.x >> 3) * 128;
    if (rows0 >= ce) return;
    int oe = off[e];
    int o0 = blockIdx.y * 128;
    int tid = threadIdx.x;

    __shared__ u16 As0[128 * 32]; __shared__ u16 As1[128 * 32];
    __shared__ u16 Bs0[128 * 32]; __shared__ u16 Bs1[128 * 32];

    int swz = ((tid & 3) ^ ((tid >> 3) & 3)) * 8;
    const u16* ab0; const u16* ab1; const u16* bb0; const u16* bb1;
    {
        int rl0 = tid >> 2, rl1 = 64 + (tid >> 2);
        int ar0 = min(oe + rows0 + rl0, NPAIR - 1);
        int ar1 = min(oe + rows0 + rl1, NPAIR - 1);
        ab0 = inter + (size_t)ar0 * DHP + swz;
        ab1 = inter + (size_t)ar1 * DHP + swz;
        bb0 = wd16 + ((size_t)e * DO + (o0 + rl0)) * DHP + swz;
        bb1 = wd16 + ((size_t)e * DO + (o0 + rl1)) * DHP + swz;
    }

    int wid = tid >> 6, lane = tid & 63;
    int wm = wid >> 1, wn = wid & 1;
    int rA = wm * 64 + (lane & 15);
    int rB = wn * 64 + (lane & 15);
    int colb = (((lane >> 4) ^ ((lane >> 1) & 3)) & 3) * 8;

    f32x4 acc[4][4];
    f32x4 vz = {0.f, 0.f, 0.f, 0.f};
#pragma unroll
    for (int m = 0; m < 4; ++m)
#pragma unroll
        for (int n = 0; n < 4; ++n) acc[m][n] = vz;

    int ldst = tid * 8;

#define S2_STAGE(A_, B_, K0)                                       \
    do {                                                           \
        gload16(ab0 + (K0), &A_[ldst]);                            \
        gload16(ab1 + (K0), &A_[2048 + ldst]);                     \
        gload16(bb0 + (K0), &B_[ldst]);                            \
        gload16(bb1 + (K0), &B_[2048 + ldst]);                     \
    } while (0)

#define S2_COMPUTE(A_, B_)                                         \
    do {                                                           \
        bf16x8 a[4], b[4];                                         \
        _Pragma("unroll")                                          \
        for (int m = 0; m < 4; ++m)                                \
            a[m] = *(const bf16x8*)&A_[(rA + m * 16) * 32 + colb]; \
        _Pragma("unroll")                                          \
        for (int n = 0; n < 4; ++n)                                \
            b[n] = *(const bf16x8*)&B_[(rB + n * 16) * 32 + colb]; \
        _Pragma("unroll")                                          \
        for (int m = 0; m < 4; ++m)                                \
            _Pragma("unroll")                                      \
            for (int n = 0; n < 4; ++n)                            \
                acc[m][n] = __builtin_amdgcn_mfma_f32_16x16x32_bf16(a[m], b[n], acc[m][n], 0, 0, 0); \
    } while (0)

    S2_STAGE(As0, Bs0, 0);
    VMCNT0();
    __builtin_amdgcn_s_barrier();

    const int NT = DHP / 32;   // 44, even
    for (int kt = 0; kt < NT; kt += 2) {
        if (kt + 1 < NT) S2_STAGE(As1, Bs1, (kt + 1) * 32);
        S2_COMPUTE(As0, Bs0);
        VMCNT0();
        __builtin_amdgcn_s_barrier();
        if (kt + 2 < NT) S2_STAGE(As0, Bs0, (kt + 2) * 32);
        S2_COMPUTE(As1, Bs1);
        VMCNT0();
        __builtin_amdgcn_s_barrier();
    }
#undef S2_STAGE
#undef S2_COMPUTE

    int rmax = ce - rows0;
#pragma unroll
    for (int m = 0; m < 4; ++m) {
#pragma unroll
        for (int r = 0; r < 4; ++r) {
            int rl = wm * 64 + m * 16 + (lane >> 4) * 4 + r;
            if (rl >= rmax) continue;
            int t = tok[oe + rows0 + rl];
            float* yr = y + (size_t)t * DO + o0 + wn * 64 + (lane & 15);
#pragma unroll
            for (int n = 0; n < 4; ++n)
                unsafeAtomicAdd(yr + n * 16, acc[m][n][r]);
        }
    }
}

// ---------------- host launch ----------------
extern "C" void kernel_launch(void* const* d_in, const int* in_sizes, int n_in,
                              void* d_out, int out_size, void* d_ws, size_t ws_size,
                              hipStream_t stream)
{
    const float* x  = (const float*)d_in[0];
    const float* gw = (const float*)d_in[1];
    const float* wg = (const float*)d_in[2];
    const float* bg = (const float*)d_in[3];
    const float* wu = (const float*)d_in[4];
    const float* bu = (const float*)d_in[5];
    const float* wd = (const float*)d_in[6];
    const float* bd = (const float*)d_in[7];
    float* y = (float*)d_out;
    float* loss = y + (size_t)TN * DO;

    uint8_t* ws = (uint8_t*)d_ws;
    u16*   x16   = (u16*)(ws + 0);             // 33,554,432
    u16*   inter = (u16*)(ws + 33554432ull);   // 23,068,672 (stride DHP)
    u16*   wg16  = (u16*)(ws + 56623104ull);   // 90,177,536
    u16*   wu16  = (u16*)(ws + 146800640ull);  // 90,177,536
    u16*   wd16  = (u16*)(ws + 236978176ull);  // 92,274,688 (stride DHP, pad zeroed)
    int*   tok   = (int*)(ws + 329252864ull);
    float* sc    = (float*)(ws + 329285632ull);
    int*   tke   = (int*)(ws + 329318400ull);
    float* tks   = (float*)(ws + 329351168ull);
    int*   misc  = (int*)(ws + 329383936ull);
    int* cnt = misc; int* fill = misc + 8; int* off = misc + 16;
    float* imp = (float*)(misc + 24);

    hipMemsetAsync(misc, 0, 128, stream);
    k_cvt<<<22016, 256, 0, stream>>>(wg, wg16, 5636096);
    k_cvt<<<22016, 256, 0, stream>>>(wu, wu16, 5636096);
    k_cvt_wd<<<22528, 256, 0, stream>>>(wd, wd16);
    k_gate<<<TN, 256, 0, stream>>>(x, gw, x16, tke, tks, cnt, imp);
    k_finalize<<<1, 64, 0, stream>>>(cnt, imp, off, loss);
    k_scatter<<<TN / 256, 256, 0, stream>>>(tke, tks, off, fill, tok, sc);
    k_yinit<<<TN, 256, 0, stream>>>(tke, tks, bd, y);
    k_stage1d<<<dim3(256, 11), 256, 0, stream>>>(x16, wg16, wu16, bg, bu, cnt, off, tok, sc, inter);
    k_stage2d<<<dim3(256, 32), 256, 0, stream>>>(inter, wd16, cnt, off, tok, y);
}

// Round 5
// 1804.798 us; speedup vs baseline: 1.0189x; 1.0189x over previous
//
#include <hip/hip_runtime.h>
#include <hip/hip_bf16.h>
#include <stdint.h>

#define TN 4096      // tokens (B*S)
#define DI 4096      // input dim
#define DH 1376      // GLU hidden dim
#define DHP 1408     // padded hidden (22*64, 44*32)
#define DO 4096      // output dim
#define NE 8         // experts
#define NPAIR 8192   // TN * K

typedef unsigned short u16;
typedef __bf16 bf16x8 __attribute__((ext_vector_type(8)));
typedef float f32x4 __attribute__((ext_vector_type(4)));
typedef uint32_t u32x4 __attribute__((ext_vector_type(4)));

__device__ __forceinline__ uint32_t pack2bf(float a, float b) {
    union { float f; uint32_t u; } ua, ub;
    ua.f = a; ub.f = b;
    uint32_t lo = (ua.u + 0x7fffu + ((ua.u >> 16) & 1u)) >> 16;
    uint32_t hi = (ub.u + 0x7fffu + ((ub.u >> 16) & 1u)) >> 16;
    return lo | (hi << 16);
}
__device__ __forceinline__ u16 f2bf(float a) {
    union { float f; uint32_t u; } ua; ua.f = a;
    return (u16)((ua.u + 0x7fffu + ((ua.u >> 16) & 1u)) >> 16);
}
__device__ __forceinline__ void gload16(const void* g, void* l) {
    __builtin_amdgcn_global_load_lds(
        (const __attribute__((address_space(1))) void*)g,
        (__attribute__((address_space(3))) void*)l, 16, 0, 0);
}

// ---------------- weight converters ----------------
__global__ __launch_bounds__(256) void k_cvt(const float* __restrict__ src,
                                             u16* __restrict__ dst, int n8)
{
    int i = blockIdx.x * 256 + threadIdx.x;
    if (i >= n8) return;
    const float4* s = (const float4*)(src + (size_t)i * 8);
    float4 a = s[0], b = s[1];
    u32x4 q = {pack2bf(a.x, a.y), pack2bf(a.z, a.w), pack2bf(b.x, b.y), pack2bf(b.z, b.w)};
    *(u32x4*)(dst + (size_t)i * 8) = q;
}

// wd [8][4096][1376] f32 -> wd16 [8][4096][1408] bf16 (pad cols zeroed)
__global__ __launch_bounds__(256) void k_cvt_wd(const float* __restrict__ src,
                                                u16* __restrict__ dst)
{
    int i = blockIdx.x * 256 + threadIdx.x;
    int row = i / 176, c8 = (i % 176) * 8;
    u32x4 q = {0u, 0u, 0u, 0u};
    if (c8 < DH) {
        const float4* s = (const float4*)(src + (size_t)row * DH + c8);
        float4 a = s[0], b = s[1];
        q = (u32x4){pack2bf(a.x, a.y), pack2bf(a.z, a.w), pack2bf(b.x, b.y), pack2bf(b.z, b.w)};
    }
    *(u32x4*)(dst + (size_t)row * DHP + c8) = q;
}

// ---------------- Kernel 1: gate (f64-accurate) + x -> bf16 ----------------
__global__ __launch_bounds__(256) void k_gate(
    const float* __restrict__ x, const float* __restrict__ gw,
    u16* __restrict__ x16, int* __restrict__ tke, float* __restrict__ tks,
    int* __restrict__ cnt, float* __restrict__ imp)
{
    int t = blockIdx.x, tid = threadIdx.x;
    const float* xr = x + (size_t)t * DI;
    double acc[NE];
#pragma unroll
    for (int e = 0; e < NE; ++e) acc[e] = 0.0;
#pragma unroll
    for (int j = 0; j < 4; ++j) {
        int i4 = (j * 256 + tid) * 4;
        float4 xv = *(const float4*)(xr + i4);
        uint2 p; p.x = pack2bf(xv.x, xv.y); p.y = pack2bf(xv.z, xv.w);
        *(uint2*)(x16 + (size_t)t * DI + i4) = p;
#pragma unroll
        for (int e = 0; e < NE; ++e) {
            float4 wv = *(const float4*)(gw + (size_t)e * DI + i4);
            acc[e] = fma((double)xv.x, (double)wv.x, acc[e]);
            acc[e] = fma((double)xv.y, (double)wv.y, acc[e]);
            acc[e] = fma((double)xv.z, (double)wv.z, acc[e]);
            acc[e] = fma((double)xv.w, (double)wv.w, acc[e]);
        }
    }
#pragma unroll
    for (int o = 32; o > 0; o >>= 1)
#pragma unroll
        for (int e = 0; e < NE; ++e) acc[e] += __shfl_down(acc[e], o, 64);
    __shared__ double lred[4][NE];
    if ((tid & 63) == 0)
#pragma unroll
        for (int e = 0; e < NE; ++e) lred[tid >> 6][e] = acc[e];
    __syncthreads();
    if (tid == 0) {
        double lg[NE];
#pragma unroll
        for (int e = 0; e < NE; ++e) lg[e] = lred[0][e] + lred[1][e] + lred[2][e] + lred[3][e];
        int e1 = 0;
        for (int e = 1; e < NE; ++e) if (lg[e] > lg[e1]) e1 = e;
        int e2 = -1;
        for (int e = 0; e < NE; ++e) { if (e == e1) continue; if (e2 < 0 || lg[e] > lg[e2]) e2 = e; }
        float d = (float)(lg[e2] - lg[e1]);
        float ed = expf(d);
        float s1 = 1.0f / (1.0f + ed);
        float s2 = ed / (1.0f + ed);
        tke[2 * t] = e1; tke[2 * t + 1] = e2;
        tks[2 * t] = s1; tks[2 * t + 1] = s2;
        atomicAdd(&cnt[e1], 1); atomicAdd(&cnt[e2], 1);
        unsafeAtomicAdd(&imp[e1], s1); unsafeAtomicAdd(&imp[e2], s2);
    }
}

// ---------------- Kernel 2: offsets + gate_loss ----------------
__global__ void k_finalize(const int* __restrict__ cnt, const float* __restrict__ imp,
                           int* __restrict__ off, float* __restrict__ loss_out)
{
    if (threadIdx.x == 0 && blockIdx.x == 0) {
        int o = 0;
        for (int e = 0; e < NE; ++e) { off[e] = o; o += cnt[e]; }
        float m1 = 0.f, m2 = 0.f;
        for (int e = 0; e < NE; ++e) { m1 += imp[e]; m2 += (float)cnt[e]; }
        m1 *= 0.125f; m2 *= 0.125f;
        float v1 = 0.f, v2 = 0.f;
        for (int e = 0; e < NE; ++e) {
            float d1 = imp[e] - m1, d2 = (float)cnt[e] - m2;
            v1 += d1 * d1; v2 += d2 * d2;
        }
        v1 /= 7.0f; v2 /= 7.0f;
        float cv1 = v1 / (m1 * m1 + 1e-10f);
        float cv2 = v2 / (m2 * m2 + 1e-10f);
        *loss_out = 0.01f * (cv1 + cv2);
    }
}

// ---------------- Kernel 3: scatter tokens ----------------
__global__ __launch_bounds__(256) void k_scatter(
    const int* __restrict__ tke, const float* __restrict__ tks,
    const int* __restrict__ off, int* __restrict__ fill,
    int* __restrict__ tok, float* __restrict__ sc)
{
    int t = blockIdx.x * 256 + threadIdx.x;
    if (t >= TN) return;
#pragma unroll
    for (int k = 0; k < 2; ++k) {
        int e = tke[2 * t + k];
        int pos = off[e] + atomicAdd(&fill[e], 1);
        tok[pos] = t; sc[pos] = tks[2 * t + k];
    }
}

// ---------------- Kernel 4: y init with score-weighted b_down ----------------
__global__ __launch_bounds__(256) void k_yinit(
    const int* __restrict__ tke, const float* __restrict__ tks,
    const float* __restrict__ bd, float* __restrict__ y)
{
    int t = blockIdx.x, tid = threadIdx.x;
    int e1 = tke[2 * t], e2 = tke[2 * t + 1];
    float s1 = tks[2 * t], s2 = tks[2 * t + 1];
    const float4* b1 = (const float4*)(bd + (size_t)e1 * DO);
    const float4* b2 = (const float4*)(bd + (size_t)e2 * DO);
    float4* yr = (float4*)(y + (size_t)t * DO);
#pragma unroll
    for (int j = 0; j < 4; ++j) {
        int i = j * 256 + tid;
        float4 a = b1[i], b = b2[i], r;
        r.x = s1 * a.x + s2 * b.x; r.y = s1 * a.y + s2 * b.y;
        r.z = s1 * a.z + s2 * b.z; r.w = s1 * a.w + s2 * b.w;
        yr[i] = r;
    }
}

// ============ pipelined bf16 GEMM kernels ============
// LDS tiles [128][32] bf16 (64B rows, 4 x 16B slots). Swizzle: phys slot
// p of row r holds logical col16-block (p ^ ((r>>1)&3)) -> reads are 2-way
// bank aliased (free). Rule 21: linear LDS dest, inverse-swizzled GLOBAL
// source, same XOR on read.
// CRITICAL (m104/m108, round-3/4 post-mortem): global_load_lds LDS dest
// must be WAVE-UNIFORM (&buf[half*2048 + wid*512]); HW adds lane*16.
// Passing a per-lane dest (tid*8) forces a waterfall lowering: 64x issue,
// scratch traffic, 4x slowdown — even though results stay correct.
// Pipeline: separate __shared__ objects per buffer, static 2x-unrolled
// loop, one __syncthreads() per phase AFTER the MFMA cluster.

// ---------------- stage-1: fused GLU GEMM ----------------
__global__ __launch_bounds__(256, 3) void k_stage1e(
    const u16* __restrict__ x16,
    const u16* __restrict__ wg16, const u16* __restrict__ wu16,
    const float* __restrict__ bg, const float* __restrict__ bu,
    const int* __restrict__ cnt, const int* __restrict__ off,
    const int* __restrict__ tok, const float* __restrict__ sc,
    u16* __restrict__ inter)
{
    int e = blockIdx.x & 7;               // expert -> XCD affinity
    int ce = cnt[e];
    int rows0 = (blockIdx.x >> 3) * 128;
    if (rows0 >= ce) return;
    int oe = off[e];
    int h0 = blockIdx.y * 128;
    int tid = threadIdx.x;

    __shared__ u16 As0[128 * 32]; __shared__ u16 As1[128 * 32];
    __shared__ u16 Gs0[128 * 32]; __shared__ u16 Gs1[128 * 32];
    __shared__ u16 Us0[128 * 32]; __shared__ u16 Us1[128 * 32];

    // staging: thread t fills LDS row (t>>2)+{0,64}, phys slot (t&3);
    // global source logical col16-block = (t&3) ^ ((t>>3)&3)
    int swz = ((tid & 3) ^ ((tid >> 3) & 3)) * 8;
    const u16* ab0; const u16* ab1; const u16* gb0; const u16* gb1;
    const u16* ub0; const u16* ub1;
    {
        int rl0 = tid >> 2, rl1 = 64 + (tid >> 2);
        int rg0 = oe + min(rows0 + rl0, ce - 1);
        int rg1 = oe + min(rows0 + rl1, ce - 1);
        ab0 = x16 + (size_t)tok[rg0] * DI + swz;
        ab1 = x16 + (size_t)tok[rg1] * DI + swz;
        int hr0 = min(h0 + rl0, DH - 1), hr1 = min(h0 + rl1, DH - 1);
        gb0 = wg16 + ((size_t)e * DH + hr0) * DI + swz;
        gb1 = wg16 + ((size_t)e * DH + hr1) * DI + swz;
        ub0 = wu16 + ((size_t)e * DH + hr0) * DI + swz;
        ub1 = wu16 + ((size_t)e * DH + hr1) * DI + swz;
    }

    int wid = tid >> 6, lane = tid & 63;
    int ldsw = wid * 512;                 // u16; WAVE-UNIFORM dest base
    int wm = wid >> 1, wn = wid & 1;
    int rA = wm * 64 + (lane & 15);
    int rB = wn * 64 + (lane & 15);
    int colb = (((lane >> 4) ^ ((lane >> 1) & 3)) & 3) * 8;  // phys slot on read

    f32x4 accg[4][4], accu[4][4];
    f32x4 vz = {0.f, 0.f, 0.f, 0.f};
#pragma unroll
    for (int m = 0; m < 4; ++m)
#pragma unroll
        for (int n = 0; n < 4; ++n) { accg[m][n] = vz; accu[m][n] = vz; }

#define S1_STAGE(A_, G_, U_, K0)                                   \
    do {                                                           \
        gload16(ab0 + (K0), &A_[ldsw]);                            \
        gload16(ab1 + (K0), &A_[2048 + ldsw]);                     \
        gload16(gb0 + (K0), &G_[ldsw]);                            \
        gload16(gb1 + (K0), &G_[2048 + ldsw]);                     \
        gload16(ub0 + (K0), &U_[ldsw]);                            \
        gload16(ub1 + (K0), &U_[2048 + ldsw]);                     \
    } while (0)

#define S1_COMPUTE(A_, G_, U_)                                     \
    do {                                                           \
        bf16x8 a[4], g[4], u[4];                                   \
        _Pragma("unroll")                                          \
        for (int m = 0; m < 4; ++m)                                \
            a[m] = *(const bf16x8*)&A_[(rA + m * 16) * 32 + colb]; \
        _Pragma("unroll")                                          \
        for (int n = 0; n < 4; ++n) {                              \
            g[n] = *(const bf16x8*)&G_[(rB + n * 16) * 32 + colb]; \
            u[n] = *(const bf16x8*)&U_[(rB + n * 16) * 32 + colb]; \
        }                                                          \
        _Pragma("unroll")                                          \
        for (int m = 0; m < 4; ++m)                                \
            _Pragma("unroll")                                      \
            for (int n = 0; n < 4; ++n) {                          \
                accg[m][n] = __builtin_amdgcn_mfma_f32_16x16x32_bf16(a[m], g[n], accg[m][n], 0, 0, 0); \
                accu[m][n] = __builtin_amdgcn_mfma_f32_16x16x32_bf16(a[m], u[n], accu[m][n], 0, 0, 0); \
            }                                                      \
    } while (0)

    // prologue
    S1_STAGE(As0, Gs0, Us0, 0);
    __syncthreads();

    const int NT = DI / 32;   // 128, even
    for (int kt = 0; kt < NT; kt += 2) {
        // even: prefetch buf1(kt+1), compute buf0(kt)
        if (kt + 1 < NT) S1_STAGE(As1, Gs1, Us1, (kt + 1) * 32);
        S1_COMPUTE(As0, Gs0, Us0);
        __syncthreads();
        // odd: prefetch buf0(kt+2), compute buf1(kt+1)
        if (kt + 2 < NT) S1_STAGE(As0, Gs0, Us0, (kt + 2) * 32);
        S1_COMPUTE(As1, Gs1, Us1);
        __syncthreads();
    }
#undef S1_STAGE
#undef S1_COMPUTE

    // epilogue: bias + silu + score-fold; zero-fill pad cols [DH, DHP)
    int rmax = ce - rows0;
    float bgv[4], buv[4];
    int hc[4]; bool hok[4];
#pragma unroll
    for (int n = 0; n < 4; ++n) {
        hc[n] = h0 + wn * 64 + n * 16 + (lane & 15);
        hok[n] = hc[n] < DH;
        bgv[n] = hok[n] ? bg[e * DH + hc[n]] : 0.f;
        buv[n] = hok[n] ? bu[e * DH + hc[n]] : 0.f;
    }
#pragma unroll
    for (int m = 0; m < 4; ++m) {
#pragma unroll
        for (int r = 0; r < 4; ++r) {
            int rl = wm * 64 + m * 16 + (lane >> 4) * 4 + r;
            if (rl < rmax) {
                int rg = oe + rows0 + rl;
                float s = sc[rg];
                size_t rowb = (size_t)rg * DHP;
#pragma unroll
                for (int n = 0; n < 4; ++n) {
                    float v = 0.f;
                    if (hok[n]) {
                        float gv = accg[m][n][r] + bgv[n];
                        float uv = accu[m][n][r] + buv[n];
                        float sig = 1.0f / (1.0f + __expf(-gv));
                        v = s * gv * sig * uv;
                    }
                    inter[rowb + hc[n]] = f2bf(v);
                }
            }
        }
    }
}

// ---------------- stage-2: down-proj GEMM + atomic scatter ----------------
__global__ __launch_bounds__(256, 4) void k_stage2e(
    const u16* __restrict__ inter, const u16* __restrict__ wd16,
    const int* __restrict__ cnt, const int* __restrict__ off,
    const int* __restrict__ tok, float* __restrict__ y)
{
    int e = blockIdx.x & 7;
    int ce = cnt[e];
    int rows0 = (blockIdx.x >> 3) * 128;
    if (rows0 >= ce) return;
    int oe = off[e];
    int o0 = blockIdx.y * 128;
    int tid = threadIdx.x;

    __shared__ u16 As0[128 * 32]; __shared__ u16 As1[128 * 32];
    __shared__ u16 Bs0[128 * 32]; __shared__ u16 Bs1[128 * 32];

    int swz = ((tid & 3) ^ ((tid >> 3) & 3)) * 8;
    const u16* ab0; const u16* ab1; const u16* bb0; const u16* bb1;
    {
        int rl0 = tid >> 2, rl1 = 64 + (tid >> 2);
        int ar0 = min(oe + rows0 + rl0, NPAIR - 1);
        int ar1 = min(oe + rows0 + rl1, NPAIR - 1);
        ab0 = inter + (size_t)ar0 * DHP + swz;
        ab1 = inter + (size_t)ar1 * DHP + swz;
        bb0 = wd16 + ((size_t)e * DO + (o0 + rl0)) * DHP + swz;
        bb1 = wd16 + ((size_t)e * DO + (o0 + rl1)) * DHP + swz;
    }

    int wid = tid >> 6, lane = tid & 63;
    int ldsw = wid * 512;                 // u16; WAVE-UNIFORM dest base
    int wm = wid >> 1, wn = wid & 1;
    int rA = wm * 64 + (lane & 15);
    int rB = wn * 64 + (lane & 15);
    int colb = (((lane >> 4) ^ ((lane >> 1) & 3)) & 3) * 8;

    f32x4 acc[4][4];
    f32x4 vz = {0.f, 0.f, 0.f, 0.f};
#pragma unroll
    for (int m = 0; m < 4; ++m)
#pragma unroll
        for (int n = 0; n < 4; ++n) acc[m][n] = vz;

#define S2_STAGE(A_, B_, K0)                                       \
    do {                                                           \
        gload16(ab0 + (K0), &A_[ldsw]);                            \
        gload16(ab1 + (K0), &A_[2048 + ldsw]);                     \
        gload16(bb0 + (K0), &B_[ldsw]);                            \
        gload16(bb1 + (K0), &B_[2048 + ldsw]);                     \
    } while (0)

#define S2_COMPUTE(A_, B_)                                         \
    do {                                                           \
        bf16x8 a[4], b[4];                                         \
        _Pragma("unroll")                                          \
        for (int m = 0; m < 4; ++m)                                \
            a[m] = *(const bf16x8*)&A_[(rA + m * 16) * 32 + colb]; \
        _Pragma("unroll")                                          \
        for (int n = 0; n < 4; ++n)                                \
            b[n] = *(const bf16x8*)&B_[(rB + n * 16) * 32 + colb]; \
        _Pragma("unroll")                                          \
        for (int m = 0; m < 4; ++m)                                \
            _Pragma("unroll")                                      \
            for (int n = 0; n < 4; ++n)                            \
                acc[m][n] = __builtin_amdgcn_mfma_f32_16x16x32_bf16(a[m], b[n], acc[m][n], 0, 0, 0); \
    } while (0)

    S2_STAGE(As0, Bs0, 0);
    __syncthreads();

    const int NT = DHP / 32;   // 44, even
    for (int kt = 0; kt < NT; kt += 2) {
        if (kt + 1 < NT) S2_STAGE(As1, Bs1, (kt + 1) * 32);
        S2_COMPUTE(As0, Bs0);
        __syncthreads();
        if (kt + 2 < NT) S2_STAGE(As0, Bs0, (kt + 2) * 32);
        S2_COMPUTE(As1, Bs1);
        __syncthreads();
    }
#undef S2_STAGE
#undef S2_COMPUTE

    int rmax = ce - rows0;
#pragma unroll
    for (int m = 0; m < 4; ++m) {
#pragma unroll
        for (int r = 0; r < 4; ++r) {
            int rl = wm * 64 + m * 16 + (lane >> 4) * 4 + r;
            if (rl >= rmax) continue;
            int t = tok[oe + rows0 + rl];
            float* yr = y + (size_t)t * DO + o0 + wn * 64 + (lane & 15);
#pragma unroll
            for (int n = 0; n < 4; ++n)
                unsafeAtomicAdd(yr + n * 16, acc[m][n][r]);
        }
    }
}

// ---------------- host launch ----------------
extern "C" void kernel_launch(void* const* d_in, const int* in_sizes, int n_in,
                              void* d_out, int out_size, void* d_ws, size_t ws_size,
                              hipStream_t stream)
{
    const float* x  = (const float*)d_in[0];
    const float* gw = (const float*)d_in[1];
    const float* wg = (const float*)d_in[2];
    const float* bg = (const float*)d_in[3];
    const float* wu = (const float*)d_in[4];
    const float* bu = (const float*)d_in[5];
    const float* wd = (const float*)d_in[6];
    const float* bd = (const float*)d_in[7];
    float* y = (float*)d_out;
    float* loss = y + (size_t)TN * DO;

    uint8_t* ws = (uint8_t*)d_ws;
    u16*   x16   = (u16*)(ws + 0);             // 33,554,432
    u16*   inter = (u16*)(ws + 33554432ull);   // 23,068,672 (stride DHP)
    u16*   wg16  = (u16*)(ws + 56623104ull);   // 90,177,536
    u16*   wu16  = (u16*)(ws + 146800640ull);  // 90,177,536
    u16*   wd16  = (u16*)(ws + 236978176ull);  // 92,274,688 (stride DHP, pad zeroed)
    int*   tok   = (int*)(ws + 329252864ull);
    float* sc    = (float*)(ws + 329285632ull);
    int*   tke   = (int*)(ws + 329318400ull);
    float* tks   = (float*)(ws + 329351168ull);
    int*   misc  = (int*)(ws + 329383936ull);
    int* cnt = misc; int* fill = misc + 8; int* off = misc + 16;
    float* imp = (float*)(misc + 24);

    hipMemsetAsync(misc, 0, 128, stream);
    k_cvt<<<22016, 256, 0, stream>>>(wg, wg16, 5636096);
    k_cvt<<<22016, 256, 0, stream>>>(wu, wu16, 5636096);
    k_cvt_wd<<<22528, 256, 0, stream>>>(wd, wd16);
    k_gate<<<TN, 256, 0, stream>>>(x, gw, x16, tke, tks, cnt, imp);
    k_finalize<<<1, 64, 0, stream>>>(cnt, imp, off, loss);
    k_scatter<<<TN / 256, 256, 0, stream>>>(tke, tks, off, fill, tok, sc);
    k_yinit<<<TN, 256, 0, stream>>>(tke, tks, bd, y);
    k_stage1e<<<dim3(256, 11), 256, 0, stream>>>(x16, wg16, wu16, bg, bu, cnt, off, tok, sc, inter);
    k_stage2e<<<dim3(256, 32), 256, 0, stream>>>(inter, wd16, cnt, off, tok, y);
}

// Round 6
// 801.222 us; speedup vs baseline: 2.2951x; 2.2526x over previous
//
#include <hip/hip_runtime.h>
#include <hip/hip_bf16.h>
#include <stdint.h>

#define TN 4096      // tokens (B*S)
#define DI 4096      // input dim
#define DH 1376      // GLU hidden dim
#define DHP 1408     // padded hidden (22*64, 44*32)
#define DO 4096      // output dim
#define NE 8         // experts
#define NPAIR 8192   // TN * K

typedef unsigned short u16;
typedef __bf16 bf16x8 __attribute__((ext_vector_type(8)));
typedef float f32x4 __attribute__((ext_vector_type(4)));
typedef uint32_t u32x4 __attribute__((ext_vector_type(4)));

__device__ __forceinline__ uint32_t pack2bf(float a, float b) {
    union { float f; uint32_t u; } ua, ub;
    ua.f = a; ub.f = b;
    uint32_t lo = (ua.u + 0x7fffu + ((ua.u >> 16) & 1u)) >> 16;
    uint32_t hi = (ub.u + 0x7fffu + ((ub.u >> 16) & 1u)) >> 16;
    return lo | (hi << 16);
}
__device__ __forceinline__ u16 f2bf(float a) {
    union { float f; uint32_t u; } ua; ua.f = a;
    return (u16)((ua.u + 0x7fffu + ((ua.u >> 16) & 1u)) >> 16);
}
__device__ __forceinline__ void gload16(const void* g, void* l) {
    __builtin_amdgcn_global_load_lds(
        (const __attribute__((address_space(1))) void*)g,
        (__attribute__((address_space(3))) void*)l, 16, 0, 0);
}

// ---------------- weight converters ----------------
__global__ __launch_bounds__(256) void k_cvt(const float* __restrict__ src,
                                             u16* __restrict__ dst, int n8)
{
    int i = blockIdx.x * 256 + threadIdx.x;
    if (i >= n8) return;
    const float4* s = (const float4*)(src + (size_t)i * 8);
    float4 a = s[0], b = s[1];
    u32x4 q = {pack2bf(a.x, a.y), pack2bf(a.z, a.w), pack2bf(b.x, b.y), pack2bf(b.z, b.w)};
    *(u32x4*)(dst + (size_t)i * 8) = q;
}

// wd [8][4096][1376] f32 -> wd16 [8][4096][1408] bf16 (pad cols zeroed)
__global__ __launch_bounds__(256) void k_cvt_wd(const float* __restrict__ src,
                                                u16* __restrict__ dst)
{
    int i = blockIdx.x * 256 + threadIdx.x;
    int row = i / 176, c8 = (i % 176) * 8;
    u32x4 q = {0u, 0u, 0u, 0u};
    if (c8 < DH) {
        const float4* s = (const float4*)(src + (size_t)row * DH + c8);
        float4 a = s[0], b = s[1];
        q = (u32x4){pack2bf(a.x, a.y), pack2bf(a.z, a.w), pack2bf(b.x, b.y), pack2bf(b.z, b.w)};
    }
    *(u32x4*)(dst + (size_t)row * DHP + c8) = q;
}

// ---------------- Kernel 1: gate (f64-accurate) + x -> bf16 ----------------
__global__ __launch_bounds__(256) void k_gate(
    const float* __restrict__ x, const float* __restrict__ gw,
    u16* __restrict__ x16, int* __restrict__ tke, float* __restrict__ tks,
    int* __restrict__ cnt, float* __restrict__ imp)
{
    int t = blockIdx.x, tid = threadIdx.x;
    const float* xr = x + (size_t)t * DI;
    double acc[NE];
#pragma unroll
    for (int e = 0; e < NE; ++e) acc[e] = 0.0;
#pragma unroll
    for (int j = 0; j < 4; ++j) {
        int i4 = (j * 256 + tid) * 4;
        float4 xv = *(const float4*)(xr + i4);
        uint2 p; p.x = pack2bf(xv.x, xv.y); p.y = pack2bf(xv.z, xv.w);
        *(uint2*)(x16 + (size_t)t * DI + i4) = p;
#pragma unroll
        for (int e = 0; e < NE; ++e) {
            float4 wv = *(const float4*)(gw + (size_t)e * DI + i4);
            acc[e] = fma((double)xv.x, (double)wv.x, acc[e]);
            acc[e] = fma((double)xv.y, (double)wv.y, acc[e]);
            acc[e] = fma((double)xv.z, (double)wv.z, acc[e]);
            acc[e] = fma((double)xv.w, (double)wv.w, acc[e]);
        }
    }
#pragma unroll
    for (int o = 32; o > 0; o >>= 1)
#pragma unroll
        for (int e = 0; e < NE; ++e) acc[e] += __shfl_down(acc[e], o, 64);
    __shared__ double lred[4][NE];
    if ((tid & 63) == 0)
#pragma unroll
        for (int e = 0; e < NE; ++e) lred[tid >> 6][e] = acc[e];
    __syncthreads();
    if (tid == 0) {
        double lg[NE];
#pragma unroll
        for (int e = 0; e < NE; ++e) lg[e] = lred[0][e] + lred[1][e] + lred[2][e] + lred[3][e];
        int e1 = 0;
        for (int e = 1; e < NE; ++e) if (lg[e] > lg[e1]) e1 = e;
        int e2 = -1;
        for (int e = 0; e < NE; ++e) { if (e == e1) continue; if (e2 < 0 || lg[e] > lg[e2]) e2 = e; }
        float d = (float)(lg[e2] - lg[e1]);
        float ed = expf(d);
        float s1 = 1.0f / (1.0f + ed);
        float s2 = ed / (1.0f + ed);
        tke[2 * t] = e1; tke[2 * t + 1] = e2;
        tks[2 * t] = s1; tks[2 * t + 1] = s2;
        atomicAdd(&cnt[e1], 1); atomicAdd(&cnt[e2], 1);
        unsafeAtomicAdd(&imp[e1], s1); unsafeAtomicAdd(&imp[e2], s2);
    }
}

// ---------------- Kernel 2: offsets + gate_loss ----------------
__global__ void k_finalize(const int* __restrict__ cnt, const float* __restrict__ imp,
                           int* __restrict__ off, float* __restrict__ loss_out)
{
    if (threadIdx.x == 0 && blockIdx.x == 0) {
        int o = 0;
        for (int e = 0; e < NE; ++e) { off[e] = o; o += cnt[e]; }
        float m1 = 0.f, m2 = 0.f;
        for (int e = 0; e < NE; ++e) { m1 += imp[e]; m2 += (float)cnt[e]; }
        m1 *= 0.125f; m2 *= 0.125f;
        float v1 = 0.f, v2 = 0.f;
        for (int e = 0; e < NE; ++e) {
            float d1 = imp[e] - m1, d2 = (float)cnt[e] - m2;
            v1 += d1 * d1; v2 += d2 * d2;
        }
        v1 /= 7.0f; v2 /= 7.0f;
        float cv1 = v1 / (m1 * m1 + 1e-10f);
        float cv2 = v2 / (m2 * m2 + 1e-10f);
        *loss_out = 0.01f * (cv1 + cv2);
    }
}

// ---------------- Kernel 3: scatter tokens ----------------
__global__ __launch_bounds__(256) void k_scatter(
    const int* __restrict__ tke, const float* __restrict__ tks,
    const int* __restrict__ off, int* __restrict__ fill,
    int* __restrict__ tok, float* __restrict__ sc)
{
    int t = blockIdx.x * 256 + threadIdx.x;
    if (t >= TN) return;
#pragma unroll
    for (int k = 0; k < 2; ++k) {
        int e = tke[2 * t + k];
        int pos = off[e] + atomicAdd(&fill[e], 1);
        tok[pos] = t; sc[pos] = tks[2 * t + k];
    }
}

// ---------------- Kernel 4: y init with score-weighted b_down ----------------
__global__ __launch_bounds__(256) void k_yinit(
    const int* __restrict__ tke, const float* __restrict__ tks,
    const float* __restrict__ bd, float* __restrict__ y)
{
    int t = blockIdx.x, tid = threadIdx.x;
    int e1 = tke[2 * t], e2 = tke[2 * t + 1];
    float s1 = tks[2 * t], s2 = tks[2 * t + 1];
    const float4* b1 = (const float4*)(bd + (size_t)e1 * DO);
    const float4* b2 = (const float4*)(bd + (size_t)e2 * DO);
    float4* yr = (float4*)(y + (size_t)t * DO);
#pragma unroll
    for (int j = 0; j < 4; ++j) {
        int i = j * 256 + tid;
        float4 a = b1[i], b = b2[i], r;
        r.x = s1 * a.x + s2 * b.x; r.y = s1 * a.y + s2 * b.y;
        r.z = s1 * a.z + s2 * b.z; r.w = s1 * a.w + s2 * b.w;
        yr[i] = r;
    }
}

// ============ pipelined bf16 GEMM kernels ============
// LDS tiles [128][32] bf16, XOR swizzle (phys slot p of row r holds logical
// col16-block p ^ ((r>>1)&3)); rule 21 both-sides discipline.
// Pipeline: separate __shared__ objects per buffer, static 2x-unrolled loop,
// one __syncthreads() per phase placed AFTER the MFMA cluster, so the
// prefetch issued at phase top overlaps compute.
// LESSON (rounds 3-5): __launch_bounds__ min-waves MUST stay at 2. The
// per-thread working set is ~128 acc regs (AGPR) + operands; requesting
// 3-4 waves/EU caps the unified VGPR+AGPR file at <=128/170 and the
// accumulators spill to scratch -> GBs of TCC traffic, MfmaUtil 6%.
// (VGPR_Count 108->84 and WRITE_SIZE 22MB->1.7GB were the tell.)

// ---------------- stage-1: fused GLU GEMM ----------------
__global__ __launch_bounds__(256, 2) void k_stage1f(
    const u16* __restrict__ x16,
    const u16* __restrict__ wg16, const u16* __restrict__ wu16,
    const float* __restrict__ bg, const float* __restrict__ bu,
    const int* __restrict__ cnt, const int* __restrict__ off,
    const int* __restrict__ tok, const float* __restrict__ sc,
    u16* __restrict__ inter)
{
    int e = blockIdx.x & 7;               // expert -> XCD affinity
    int ce = cnt[e];
    int rows0 = (blockIdx.x >> 3) * 128;
    if (rows0 >= ce) return;
    int oe = off[e];
    int h0 = blockIdx.y * 128;
    int tid = threadIdx.x;

    __shared__ u16 As0[128 * 32]; __shared__ u16 As1[128 * 32];
    __shared__ u16 Gs0[128 * 32]; __shared__ u16 Gs1[128 * 32];
    __shared__ u16 Us0[128 * 32]; __shared__ u16 Us1[128 * 32];

    // staging: thread t fills LDS row (t>>2)+{0,64}, phys slot (t&3);
    // global source logical col16-block = (t&3) ^ ((t>>3)&3)
    int swz = ((tid & 3) ^ ((tid >> 3) & 3)) * 8;
    const u16* ab0; const u16* ab1; const u16* gb0; const u16* gb1;
    const u16* ub0; const u16* ub1;
    {
        int rl0 = tid >> 2, rl1 = 64 + (tid >> 2);
        int rg0 = oe + min(rows0 + rl0, ce - 1);
        int rg1 = oe + min(rows0 + rl1, ce - 1);
        ab0 = x16 + (size_t)tok[rg0] * DI + swz;
        ab1 = x16 + (size_t)tok[rg1] * DI + swz;
        int hr0 = min(h0 + rl0, DH - 1), hr1 = min(h0 + rl1, DH - 1);
        gb0 = wg16 + ((size_t)e * DH + hr0) * DI + swz;
        gb1 = wg16 + ((size_t)e * DH + hr1) * DI + swz;
        ub0 = wu16 + ((size_t)e * DH + hr0) * DI + swz;
        ub1 = wu16 + ((size_t)e * DH + hr1) * DI + swz;
    }

    int wid = tid >> 6, lane = tid & 63;
    int ldsw = wid * 512;                 // wave-uniform LDS dest base (u16)
    int wm = wid >> 1, wn = wid & 1;
    int rA = wm * 64 + (lane & 15);
    int rB = wn * 64 + (lane & 15);
    int colb = (((lane >> 4) ^ ((lane >> 1) & 3)) & 3) * 8;  // phys slot on read

    f32x4 accg[4][4], accu[4][4];
    f32x4 vz = {0.f, 0.f, 0.f, 0.f};
#pragma unroll
    for (int m = 0; m < 4; ++m)
#pragma unroll
        for (int n = 0; n < 4; ++n) { accg[m][n] = vz; accu[m][n] = vz; }

#define S1_STAGE(A_, G_, U_, K0)                                   \
    do {                                                           \
        gload16(ab0 + (K0), &A_[ldsw]);                            \
        gload16(ab1 + (K0), &A_[2048 + ldsw]);                     \
        gload16(gb0 + (K0), &G_[ldsw]);                            \
        gload16(gb1 + (K0), &G_[2048 + ldsw]);                     \
        gload16(ub0 + (K0), &U_[ldsw]);                            \
        gload16(ub1 + (K0), &U_[2048 + ldsw]);                     \
    } while (0)

#define S1_COMPUTE(A_, G_, U_)                                     \
    do {                                                           \
        bf16x8 a[4], g[4], u[4];                                   \
        _Pragma("unroll")                                          \
        for (int m = 0; m < 4; ++m)                                \
            a[m] = *(const bf16x8*)&A_[(rA + m * 16) * 32 + colb]; \
        _Pragma("unroll")                                          \
        for (int n = 0; n < 4; ++n) {                              \
            g[n] = *(const bf16x8*)&G_[(rB + n * 16) * 32 + colb]; \
            u[n] = *(const bf16x8*)&U_[(rB + n * 16) * 32 + colb]; \
        }                                                          \
        _Pragma("unroll")                                          \
        for (int m = 0; m < 4; ++m)                                \
            _Pragma("unroll")                                      \
            for (int n = 0; n < 4; ++n) {                          \
                accg[m][n] = __builtin_amdgcn_mfma_f32_16x16x32_bf16(a[m], g[n], accg[m][n], 0, 0, 0); \
                accu[m][n] = __builtin_amdgcn_mfma_f32_16x16x32_bf16(a[m], u[n], accu[m][n], 0, 0, 0); \
            }                                                      \
    } while (0)

    // prologue
    S1_STAGE(As0, Gs0, Us0, 0);
    __syncthreads();

    const int NT = DI / 32;   // 128, even
    for (int kt = 0; kt < NT; kt += 2) {
        // even: prefetch buf1(kt+1), compute buf0(kt)
        if (kt + 1 < NT) S1_STAGE(As1, Gs1, Us1, (kt + 1) * 32);
        S1_COMPUTE(As0, Gs0, Us0);
        __syncthreads();
        // odd: prefetch buf0(kt+2), compute buf1(kt+1)
        if (kt + 2 < NT) S1_STAGE(As0, Gs0, Us0, (kt + 2) * 32);
        S1_COMPUTE(As1, Gs1, Us1);
        __syncthreads();
    }
#undef S1_STAGE
#undef S1_COMPUTE

    // epilogue: bias + silu + score-fold; zero-fill pad cols [DH, DHP)
    int rmax = ce - rows0;
    float bgv[4], buv[4];
    int hc[4]; bool hok[4];
#pragma unroll
    for (int n = 0; n < 4; ++n) {
        hc[n] = h0 + wn * 64 + n * 16 + (lane & 15);
        hok[n] = hc[n] < DH;
        bgv[n] = hok[n] ? bg[e * DH + hc[n]] : 0.f;
        buv[n] = hok[n] ? bu[e * DH + hc[n]] : 0.f;
    }
#pragma unroll
    for (int m = 0; m < 4; ++m) {
#pragma unroll
        for (int r = 0; r < 4; ++r) {
            int rl = wm * 64 + m * 16 + (lane >> 4) * 4 + r;
            if (rl < rmax) {
                int rg = oe + rows0 + rl;
                float s = sc[rg];
                size_t rowb = (size_t)rg * DHP;
#pragma unroll
                for (int n = 0; n < 4; ++n) {
                    float v = 0.f;
                    if (hok[n]) {
                        float gv = accg[m][n][r] + bgv[n];
                        float uv = accu[m][n][r] + buv[n];
                        float sig = 1.0f / (1.0f + __expf(-gv));
                        v = s * gv * sig * uv;
                    }
                    inter[rowb + hc[n]] = f2bf(v);
                }
            }
        }
    }
}

// ---------------- stage-2: down-proj GEMM + atomic scatter ----------------
__global__ __launch_bounds__(256, 2) void k_stage2f(
    const u16* __restrict__ inter, const u16* __restrict__ wd16,
    const int* __restrict__ cnt, const int* __restrict__ off,
    const int* __restrict__ tok, float* __restrict__ y)
{
    int e = blockIdx.x & 7;
    int ce = cnt[e];
    int rows0 = (blockIdx.x >> 3) * 128;
    if (rows0 >= ce) return;
    int oe = off[e];
    int o0 = blockIdx.y * 128;
    int tid = threadIdx.x;

    __shared__ u16 As0[128 * 32]; __shared__ u16 As1[128 * 32];
    __shared__ u16 Bs0[128 * 32]; __shared__ u16 Bs1[128 * 32];

    int swz = ((tid & 3) ^ ((tid >> 3) & 3)) * 8;
    const u16* ab0; const u16* ab1; const u16* bb0; const u16* bb1;
    {
        int rl0 = tid >> 2, rl1 = 64 + (tid >> 2);
        int ar0 = min(oe + rows0 + rl0, NPAIR - 1);
        int ar1 = min(oe + rows0 + rl1, NPAIR - 1);
        ab0 = inter + (size_t)ar0 * DHP + swz;
        ab1 = inter + (size_t)ar1 * DHP + swz;
        bb0 = wd16 + ((size_t)e * DO + (o0 + rl0)) * DHP + swz;
        bb1 = wd16 + ((size_t)e * DO + (o0 + rl1)) * DHP + swz;
    }

    int wid = tid >> 6, lane = tid & 63;
    int ldsw = wid * 512;                 // wave-uniform LDS dest base (u16)
    int wm = wid >> 1, wn = wid & 1;
    int rA = wm * 64 + (lane & 15);
    int rB = wn * 64 + (lane & 15);
    int colb = (((lane >> 4) ^ ((lane >> 1) & 3)) & 3) * 8;

    f32x4 acc[4][4];
    f32x4 vz = {0.f, 0.f, 0.f, 0.f};
#pragma unroll
    for (int m = 0; m < 4; ++m)
#pragma unroll
        for (int n = 0; n < 4; ++n) acc[m][n] = vz;

#define S2_STAGE(A_, B_, K0)                                       \
    do {                                                           \
        gload16(ab0 + (K0), &A_[ldsw]);                            \
        gload16(ab1 + (K0), &A_[2048 + ldsw]);                     \
        gload16(bb0 + (K0), &B_[ldsw]);                            \
        gload16(bb1 + (K0), &B_[2048 + ldsw]);                     \
    } while (0)

#define S2_COMPUTE(A_, B_)                                         \
    do {                                                           \
        bf16x8 a[4], b[4];                                         \
        _Pragma("unroll")                                          \
        for (int m = 0; m < 4; ++m)                                \
            a[m] = *(const bf16x8*)&A_[(rA + m * 16) * 32 + colb]; \
        _Pragma("unroll")                                          \
        for (int n = 0; n < 4; ++n)                                \
            b[n] = *(const bf16x8*)&B_[(rB + n * 16) * 32 + colb]; \
        _Pragma("unroll")                                          \
        for (int m = 0; m < 4; ++m)                                \
            _Pragma("unroll")                                      \
            for (int n = 0; n < 4; ++n)                            \
                acc[m][n] = __builtin_amdgcn_mfma_f32_16x16x32_bf16(a[m], b[n], acc[m][n], 0, 0, 0); \
    } while (0)

    S2_STAGE(As0, Bs0, 0);
    __syncthreads();

    const int NT = DHP / 32;   // 44, even
    for (int kt = 0; kt < NT; kt += 2) {
        if (kt + 1 < NT) S2_STAGE(As1, Bs1, (kt + 1) * 32);
        S2_COMPUTE(As0, Bs0);
        __syncthreads();
        if (kt + 2 < NT) S2_STAGE(As0, Bs0, (kt + 2) * 32);
        S2_COMPUTE(As1, Bs1);
        __syncthreads();
    }
#undef S2_STAGE
#undef S2_COMPUTE

    int rmax = ce - rows0;
#pragma unroll
    for (int m = 0; m < 4; ++m) {
#pragma unroll
        for (int r = 0; r < 4; ++r) {
            int rl = wm * 64 + m * 16 + (lane >> 4) * 4 + r;
            if (rl >= rmax) continue;
            int t = tok[oe + rows0 + rl];
            float* yr = y + (size_t)t * DO + o0 + wn * 64 + (lane & 15);
#pragma unroll
            for (int n = 0; n < 4; ++n)
                unsafeAtomicAdd(yr + n * 16, acc[m][n][r]);
        }
    }
}

// ---------------- host launch ----------------
extern "C" void kernel_launch(void* const* d_in, const int* in_sizes, int n_in,
                              void* d_out, int out_size, void* d_ws, size_t ws_size,
                              hipStream_t stream)
{
    const float* x  = (const float*)d_in[0];
    const float* gw = (const float*)d_in[1];
    const float* wg = (const float*)d_in[2];
    const float* bg = (const float*)d_in[3];
    const float* wu = (const float*)d_in[4];
    const float* bu = (const float*)d_in[5];
    const float* wd = (const float*)d_in[6];
    const float* bd = (const float*)d_in[7];
    float* y = (float*)d_out;
    float* loss = y + (size_t)TN * DO;

    uint8_t* ws = (uint8_t*)d_ws;
    u16*   x16   = (u16*)(ws + 0);             // 33,554,432
    u16*   inter = (u16*)(ws + 33554432ull);   // 23,068,672 (stride DHP)
    u16*   wg16  = (u16*)(ws + 56623104ull);   // 90,177,536
    u16*   wu16  = (u16*)(ws + 146800640ull);  // 90,177,536
    u16*   wd16  = (u16*)(ws + 236978176ull);  // 92,274,688 (stride DHP, pad zeroed)
    int*   tok   = (int*)(ws + 329252864ull);
    float* sc    = (float*)(ws + 329285632ull);
    int*   tke   = (int*)(ws + 329318400ull);
    float* tks   = (float*)(ws + 329351168ull);
    int*   misc  = (int*)(ws + 329383936ull);
    int* cnt = misc; int* fill = misc + 8; int* off = misc + 16;
    float* imp = (float*)(misc + 24);

    hipMemsetAsync(misc, 0, 128, stream);
    k_cvt<<<22016, 256, 0, stream>>>(wg, wg16, 5636096);
    k_cvt<<<22016, 256, 0, stream>>>(wu, wu16, 5636096);
    k_cvt_wd<<<22528, 256, 0, stream>>>(wd, wd16);
    k_gate<<<TN, 256, 0, stream>>>(x, gw, x16, tke, tks, cnt, imp);
    k_finalize<<<1, 64, 0, stream>>>(cnt, imp, off, loss);
    k_scatter<<<TN / 256, 256, 0, stream>>>(tke, tks, off, fill, tok, sc);
    k_yinit<<<TN, 256, 0, stream>>>(tke, tks, bd, y);
    k_stage1f<<<dim3(256, 11), 256, 0, stream>>>(x16, wg16, wu16, bg, bu, cnt, off, tok, sc, inter);
    k_stage2f<<<dim3(256, 32), 256, 0, stream>>>(inter, wd16, cnt, off, tok, y);
}

// Round 7
// 793.401 us; speedup vs baseline: 2.3177x; 1.0099x over previous
//
#include <hip/hip_runtime.h>
#include <hip/hip_bf16.h>
#include <stdint.h>

#define TN 4096      // tokens (B*S)
#define DI 4096      // input dim
#define DH 1376      // GLU hidden dim
#define DHP 1408     // padded hidden (22*64, 44*32)
#define DO 4096      // output dim
#define NE 8         // experts
#define NPAIR 8192   // TN * K

typedef unsigned short u16;
typedef __bf16 bf16x8 __attribute__((ext_vector_type(8)));
typedef float f32x4 __attribute__((ext_vector_type(4)));
typedef uint32_t u32x4 __attribute__((ext_vector_type(4)));

__device__ __forceinline__ uint32_t pack2bf(float a, float b) {
    union { float f; uint32_t u; } ua, ub;
    ua.f = a; ub.f = b;
    uint32_t lo = (ua.u + 0x7fffu + ((ua.u >> 16) & 1u)) >> 16;
    uint32_t hi = (ub.u + 0x7fffu + ((ub.u >> 16) & 1u)) >> 16;
    return lo | (hi << 16);
}
__device__ __forceinline__ u16 f2bf(float a) {
    union { float f; uint32_t u; } ua; ua.f = a;
    return (u16)((ua.u + 0x7fffu + ((ua.u >> 16) & 1u)) >> 16);
}
__device__ __forceinline__ void gload16(const void* g, void* l) {
    __builtin_amdgcn_global_load_lds(
        (const __attribute__((address_space(1))) void*)g,
        (__attribute__((address_space(3))) void*)l, 16, 0, 0);
}
#define MEMFENCE() asm volatile("" ::: "memory")

// ---------------- weight converters ----------------
__global__ __launch_bounds__(256) void k_cvt(const float* __restrict__ src,
                                             u16* __restrict__ dst, int n8)
{
    int i = blockIdx.x * 256 + threadIdx.x;
    if (i >= n8) return;
    const float4* s = (const float4*)(src + (size_t)i * 8);
    float4 a = s[0], b = s[1];
    u32x4 q = {pack2bf(a.x, a.y), pack2bf(a.z, a.w), pack2bf(b.x, b.y), pack2bf(b.z, b.w)};
    *(u32x4*)(dst + (size_t)i * 8) = q;
}

// wd [8][4096][1376] f32 -> wd16 [8][4096][1408] bf16 (pad cols zeroed)
__global__ __launch_bounds__(256) void k_cvt_wd(const float* __restrict__ src,
                                                u16* __restrict__ dst)
{
    int i = blockIdx.x * 256 + threadIdx.x;
    int row = i / 176, c8 = (i % 176) * 8;
    u32x4 q = {0u, 0u, 0u, 0u};
    if (c8 < DH) {
        const float4* s = (const float4*)(src + (size_t)row * DH + c8);
        float4 a = s[0], b = s[1];
        q = (u32x4){pack2bf(a.x, a.y), pack2bf(a.z, a.w), pack2bf(b.x, b.y), pack2bf(b.z, b.w)};
    }
    *(u32x4*)(dst + (size_t)row * DHP + c8) = q;
}

// ---------------- Kernel 1: gate (f64-accurate) + x -> bf16 ----------------
__global__ __launch_bounds__(256) void k_gate(
    const float* __restrict__ x, const float* __restrict__ gw,
    u16* __restrict__ x16, int* __restrict__ tke, float* __restrict__ tks,
    int* __restrict__ cnt, float* __restrict__ imp)
{
    int t = blockIdx.x, tid = threadIdx.x;
    const float* xr = x + (size_t)t * DI;
    double acc[NE];
#pragma unroll
    for (int e = 0; e < NE; ++e) acc[e] = 0.0;
#pragma unroll
    for (int j = 0; j < 4; ++j) {
        int i4 = (j * 256 + tid) * 4;
        float4 xv = *(const float4*)(xr + i4);
        uint2 p; p.x = pack2bf(xv.x, xv.y); p.y = pack2bf(xv.z, xv.w);
        *(uint2*)(x16 + (size_t)t * DI + i4) = p;
#pragma unroll
        for (int e = 0; e < NE; ++e) {
            float4 wv = *(const float4*)(gw + (size_t)e * DI + i4);
            acc[e] = fma((double)xv.x, (double)wv.x, acc[e]);
            acc[e] = fma((double)xv.y, (double)wv.y, acc[e]);
            acc[e] = fma((double)xv.z, (double)wv.z, acc[e]);
            acc[e] = fma((double)xv.w, (double)wv.w, acc[e]);
        }
    }
#pragma unroll
    for (int o = 32; o > 0; o >>= 1)
#pragma unroll
        for (int e = 0; e < NE; ++e) acc[e] += __shfl_down(acc[e], o, 64);
    __shared__ double lred[4][NE];
    if ((tid & 63) == 0)
#pragma unroll
        for (int e = 0; e < NE; ++e) lred[tid >> 6][e] = acc[e];
    __syncthreads();
    if (tid == 0) {
        double lg[NE];
#pragma unroll
        for (int e = 0; e < NE; ++e) lg[e] = lred[0][e] + lred[1][e] + lred[2][e] + lred[3][e];
        int e1 = 0;
        for (int e = 1; e < NE; ++e) if (lg[e] > lg[e1]) e1 = e;
        int e2 = -1;
        for (int e = 0; e < NE; ++e) { if (e == e1) continue; if (e2 < 0 || lg[e] > lg[e2]) e2 = e; }
        float d = (float)(lg[e2] - lg[e1]);
        float ed = expf(d);
        float s1 = 1.0f / (1.0f + ed);
        float s2 = ed / (1.0f + ed);
        tke[2 * t] = e1; tke[2 * t + 1] = e2;
        tks[2 * t] = s1; tks[2 * t + 1] = s2;
        atomicAdd(&cnt[e1], 1); atomicAdd(&cnt[e2], 1);
        unsafeAtomicAdd(&imp[e1], s1); unsafeAtomicAdd(&imp[e2], s2);
    }
}

// ---------------- Kernel 2: offsets + gate_loss ----------------
__global__ void k_finalize(const int* __restrict__ cnt, const float* __restrict__ imp,
                           int* __restrict__ off, float* __restrict__ loss_out)
{
    if (threadIdx.x == 0 && blockIdx.x == 0) {
        int o = 0;
        for (int e = 0; e < NE; ++e) { off[e] = o; o += cnt[e]; }
        float m1 = 0.f, m2 = 0.f;
        for (int e = 0; e < NE; ++e) { m1 += imp[e]; m2 += (float)cnt[e]; }
        m1 *= 0.125f; m2 *= 0.125f;
        float v1 = 0.f, v2 = 0.f;
        for (int e = 0; e < NE; ++e) {
            float d1 = imp[e] - m1, d2 = (float)cnt[e] - m2;
            v1 += d1 * d1; v2 += d2 * d2;
        }
        v1 /= 7.0f; v2 /= 7.0f;
        float cv1 = v1 / (m1 * m1 + 1e-10f);
        float cv2 = v2 / (m2 * m2 + 1e-10f);
        *loss_out = 0.01f * (cv1 + cv2);
    }
}

// ---------------- Kernel 3: scatter tokens ----------------
__global__ __launch_bounds__(256) void k_scatter(
    const int* __restrict__ tke, const float* __restrict__ tks,
    const int* __restrict__ off, int* __restrict__ fill,
    int* __restrict__ tok, float* __restrict__ sc)
{
    int t = blockIdx.x * 256 + threadIdx.x;
    if (t >= TN) return;
#pragma unroll
    for (int k = 0; k < 2; ++k) {
        int e = tke[2 * t + k];
        int pos = off[e] + atomicAdd(&fill[e], 1);
        tok[pos] = t; sc[pos] = tks[2 * t + k];
    }
}

// ---------------- Kernel 4: y init with score-weighted b_down ----------------
__global__ __launch_bounds__(256) void k_yinit(
    const int* __restrict__ tke, const float* __restrict__ tks,
    const float* __restrict__ bd, float* __restrict__ y)
{
    int t = blockIdx.x, tid = threadIdx.x;
    int e1 = tke[2 * t], e2 = tke[2 * t + 1];
    float s1 = tks[2 * t], s2 = tks[2 * t + 1];
    const float4* b1 = (const float4*)(bd + (size_t)e1 * DO);
    const float4* b2 = (const float4*)(bd + (size_t)e2 * DO);
    float4* yr = (float4*)(y + (size_t)t * DO);
#pragma unroll
    for (int j = 0; j < 4; ++j) {
        int i = j * 256 + tid;
        float4 a = b1[i], b = b2[i], r;
        r.x = s1 * a.x + s2 * b.x; r.y = s1 * a.y + s2 * b.y;
        r.z = s1 * a.z + s2 * b.z; r.w = s1 * a.w + s2 * b.w;
        yr[i] = r;
    }
}

// ============ 3-deep counted-vmcnt pipelined GEMM kernels (T3+T4+T5) ============
// LDS tiles [128][32] bf16, XOR swizzle (phys slot p of row r holds logical
// col16-block p ^ ((r>>1)&3)); rule-21 both-sides discipline; wave-uniform
// gload_lds dest; __launch_bounds__(256,2) (min-waves 3+ spills accs: r3-5).
// Pipeline: 3 buffers, 3 tiles in flight. Per phase:
//   vmcnt(2L) [tile-p landed, p+1/p+2 stay in flight] -> s_barrier ->
//   ds_read + setprio(1) MFMA setprio(0) -> s_barrier -> STAGE(tile p+3, no wait).
// Tail peeled with vmcnt(L)/vmcnt(0); out-of-range stage clamps to last tile
// (dummy, never read) so main loop is branch-free. MEMFENCE after each barrier
// pins ds_read/STAGE on the correct side of the barrier.

// ---------------- stage-1: fused GLU GEMM ----------------
__global__ __launch_bounds__(256, 2) void k_stage1g(
    const u16* __restrict__ x16,
    const u16* __restrict__ wg16, const u16* __restrict__ wu16,
    const float* __restrict__ bg, const float* __restrict__ bu,
    const int* __restrict__ cnt, const int* __restrict__ off,
    const int* __restrict__ tok, const float* __restrict__ sc,
    u16* __restrict__ inter)
{
    int e = blockIdx.x & 7;               // expert -> XCD affinity
    int ce = cnt[e];
    int rows0 = (blockIdx.x >> 3) * 128;
    if (rows0 >= ce) return;
    int oe = off[e];
    int h0 = blockIdx.y * 128;
    int tid = threadIdx.x;

    __shared__ u16 As0[128 * 32]; __shared__ u16 As1[128 * 32]; __shared__ u16 As2[128 * 32];
    __shared__ u16 Gs0[128 * 32]; __shared__ u16 Gs1[128 * 32]; __shared__ u16 Gs2[128 * 32];
    __shared__ u16 Us0[128 * 32]; __shared__ u16 Us1[128 * 32]; __shared__ u16 Us2[128 * 32];

    // staging: thread t fills LDS row (t>>2)+{0,64}, phys slot (t&3);
    // global source logical col16-block = (t&3) ^ ((t>>3)&3)
    int swz = ((tid & 3) ^ ((tid >> 3) & 3)) * 8;
    const u16* ab0; const u16* ab1; const u16* gb0; const u16* gb1;
    const u16* ub0; const u16* ub1;
    {
        int rl0 = tid >> 2, rl1 = 64 + (tid >> 2);
        int rg0 = oe + min(rows0 + rl0, ce - 1);
        int rg1 = oe + min(rows0 + rl1, ce - 1);
        ab0 = x16 + (size_t)tok[rg0] * DI + swz;
        ab1 = x16 + (size_t)tok[rg1] * DI + swz;
        int hr0 = min(h0 + rl0, DH - 1), hr1 = min(h0 + rl1, DH - 1);
        gb0 = wg16 + ((size_t)e * DH + hr0) * DI + swz;
        gb1 = wg16 + ((size_t)e * DH + hr1) * DI + swz;
        ub0 = wu16 + ((size_t)e * DH + hr0) * DI + swz;
        ub1 = wu16 + ((size_t)e * DH + hr1) * DI + swz;
    }

    int wid = tid >> 6, lane = tid & 63;
    int ldsw = wid * 512;                 // wave-uniform LDS dest base (u16)
    int wm = wid >> 1, wn = wid & 1;
    int rA = wm * 64 + (lane & 15);
    int rB = wn * 64 + (lane & 15);
    int colb = (((lane >> 4) ^ ((lane >> 1) & 3)) & 3) * 8;  // phys slot on read

    f32x4 accg[4][4], accu[4][4];
    f32x4 vz = {0.f, 0.f, 0.f, 0.f};
#pragma unroll
    for (int m = 0; m < 4; ++m)
#pragma unroll
        for (int n = 0; n < 4; ++n) { accg[m][n] = vz; accu[m][n] = vz; }

#define S1_STAGE(A_, G_, U_, K0)                                   \
    do {                                                           \
        gload16(ab0 + (K0), &A_[ldsw]);                            \
        gload16(ab1 + (K0), &A_[2048 + ldsw]);                     \
        gload16(gb0 + (K0), &G_[ldsw]);                            \
        gload16(gb1 + (K0), &G_[2048 + ldsw]);                     \
        gload16(ub0 + (K0), &U_[ldsw]);                            \
        gload16(ub1 + (K0), &U_[2048 + ldsw]);                     \
    } while (0)

#define S1_COMPUTE(A_, G_, U_)                                     \
    do {                                                           \
        bf16x8 a[4], g[4], u[4];                                   \
        _Pragma("unroll")                                          \
        for (int m = 0; m < 4; ++m)                                \
            a[m] = *(const bf16x8*)&A_[(rA + m * 16) * 32 + colb]; \
        _Pragma("unroll")                                          \
        for (int n = 0; n < 4; ++n) {                              \
            g[n] = *(const bf16x8*)&G_[(rB + n * 16) * 32 + colb]; \
            u[n] = *(const bf16x8*)&U_[(rB + n * 16) * 32 + colb]; \
        }                                                          \
        __builtin_amdgcn_s_setprio(1);                             \
        _Pragma("unroll")                                          \
        for (int m = 0; m < 4; ++m)                                \
            _Pragma("unroll")                                      \
            for (int n = 0; n < 4; ++n) {                          \
                accg[m][n] = __builtin_amdgcn_mfma_f32_16x16x32_bf16(a[m], g[n], accg[m][n], 0, 0, 0); \
                accu[m][n] = __builtin_amdgcn_mfma_f32_16x16x32_bf16(a[m], u[n], accu[m][n], 0, 0, 0); \
            }                                                      \
        __builtin_amdgcn_s_setprio(0);                             \
    } while (0)

#define S1_PHASE(A_, G_, U_, KN)                                   \
    do {                                                           \
        asm volatile("s_waitcnt vmcnt(12)" ::: "memory");          \
        __builtin_amdgcn_s_barrier();                              \
        MEMFENCE();                                                \
        S1_COMPUTE(A_, G_, U_);                                    \
        __builtin_amdgcn_s_barrier();                              \
        MEMFENCE();                                                \
        S1_STAGE(A_, G_, U_, KN);                                  \
    } while (0)

    const int NT = DI / 32;        // 128 (== 2 mod 3)
    const int KL = (NT - 1) * 32;  // clamp for dummy stages
    S1_STAGE(As0, Gs0, Us0, 0);
    S1_STAGE(As1, Gs1, Us1, 32);
    S1_STAGE(As2, Gs2, Us2, 64);

    for (int kt = 0; kt + 4 < NT; kt += 3) {
        S1_PHASE(As0, Gs0, Us0, min((kt + 3) * 32, KL));
        S1_PHASE(As1, Gs1, Us1, min((kt + 4) * 32, KL));
        S1_PHASE(As2, Gs2, Us2, min((kt + 5) * 32, KL));
    }
    // peeled tail: phases NT-2 (B0) and NT-1 (B1)
    asm volatile("s_waitcnt vmcnt(12)" ::: "memory");
    __builtin_amdgcn_s_barrier();
    MEMFENCE();
    S1_COMPUTE(As0, Gs0, Us0);
    asm volatile("s_waitcnt vmcnt(6)" ::: "memory");
    __builtin_amdgcn_s_barrier();
    MEMFENCE();
    S1_COMPUTE(As1, Gs1, Us1);
    asm volatile("s_waitcnt vmcnt(0)" ::: "memory");
#undef S1_STAGE
#undef S1_COMPUTE
#undef S1_PHASE

    // epilogue: bias + silu + score-fold; zero-fill pad cols [DH, DHP)
    int rmax = ce - rows0;
    float bgv[4], buv[4];
    int hc[4]; bool hok[4];
#pragma unroll
    for (int n = 0; n < 4; ++n) {
        hc[n] = h0 + wn * 64 + n * 16 + (lane & 15);
        hok[n] = hc[n] < DH;
        bgv[n] = hok[n] ? bg[e * DH + hc[n]] : 0.f;
        buv[n] = hok[n] ? bu[e * DH + hc[n]] : 0.f;
    }
#pragma unroll
    for (int m = 0; m < 4; ++m) {
#pragma unroll
        for (int r = 0; r < 4; ++r) {
            int rl = wm * 64 + m * 16 + (lane >> 4) * 4 + r;
            if (rl < rmax) {
                int rg = oe + rows0 + rl;
                float s = sc[rg];
                size_t rowb = (size_t)rg * DHP;
#pragma unroll
                for (int n = 0; n < 4; ++n) {
                    float v = 0.f;
                    if (hok[n]) {
                        float gv = accg[m][n][r] + bgv[n];
                        float uv = accu[m][n][r] + buv[n];
                        float sig = 1.0f / (1.0f + __expf(-gv));
                        v = s * gv * sig * uv;
                    }
                    inter[rowb + hc[n]] = f2bf(v);
                }
            }
        }
    }
}

// ---------------- stage-2: down-proj GEMM + atomic scatter ----------------
__global__ __launch_bounds__(256, 2) void k_stage2g(
    const u16* __restrict__ inter, const u16* __restrict__ wd16,
    const int* __restrict__ cnt, const int* __restrict__ off,
    const int* __restrict__ tok, float* __restrict__ y)
{
    int e = blockIdx.x & 7;
    int ce = cnt[e];
    int rows0 = (blockIdx.x >> 3) * 128;
    if (rows0 >= ce) return;
    int oe = off[e];
    int o0 = blockIdx.y * 128;
    int tid = threadIdx.x;

    __shared__ u16 As0[128 * 32]; __shared__ u16 As1[128 * 32]; __shared__ u16 As2[128 * 32];
    __shared__ u16 Bs0[128 * 32]; __shared__ u16 Bs1[128 * 32]; __shared__ u16 Bs2[128 * 32];

    int swz = ((tid & 3) ^ ((tid >> 3) & 3)) * 8;
    const u16* ab0; const u16* ab1; const u16* bb0; const u16* bb1;
    {
        int rl0 = tid >> 2, rl1 = 64 + (tid >> 2);
        int ar0 = min(oe + rows0 + rl0, NPAIR - 1);
        int ar1 = min(oe + rows0 + rl1, NPAIR - 1);
        ab0 = inter + (size_t)ar0 * DHP + swz;
        ab1 = inter + (size_t)ar1 * DHP + swz;
        bb0 = wd16 + ((size_t)e * DO + (o0 + rl0)) * DHP + swz;
        bb1 = wd16 + ((size_t)e * DO + (o0 + rl1)) * DHP + swz;
    }

    int wid = tid >> 6, lane = tid & 63;
    int ldsw = wid * 512;
    int wm = wid >> 1, wn = wid & 1;
    int rA = wm * 64 + (lane & 15);
    int rB = wn * 64 + (lane & 15);
    int colb = (((lane >> 4) ^ ((lane >> 1) & 3)) & 3) * 8;

    f32x4 acc[4][4];
    f32x4 vz = {0.f, 0.f, 0.f, 0.f};
#pragma unroll
    for (int m = 0; m < 4; ++m)
#pragma unroll
        for (int n = 0; n < 4; ++n) acc[m][n] = vz;

#define S2_STAGE(A_, B_, K0)                                       \
    do {                                                           \
        gload16(ab0 + (K0), &A_[ldsw]);                            \
        gload16(ab1 + (K0), &A_[2048 + ldsw]);                     \
        gload16(bb0 + (K0), &B_[ldsw]);                            \
        gload16(bb1 + (K0), &B_[2048 + ldsw]);                     \
    } while (0)

#define S2_COMPUTE(A_, B_)                                         \
    do {                                                           \
        bf16x8 a[4], b[4];                                         \
        _Pragma("unroll")                                          \
        for (int m = 0; m < 4; ++m)                                \
            a[m] = *(const bf16x8*)&A_[(rA + m * 16) * 32 + colb]; \
        _Pragma("unroll")                                          \
        for (int n = 0; n < 4; ++n)                                \
            b[n] = *(const bf16x8*)&B_[(rB + n * 16) * 32 + colb]; \
        __builtin_amdgcn_s_setprio(1);                             \
        _Pragma("unroll")                                          \
        for (int m = 0; m < 4; ++m)                                \
            _Pragma("unroll")                                      \
            for (int n = 0; n < 4; ++n)                            \
                acc[m][n] = __builtin_amdgcn_mfma_f32_16x16x32_bf16(a[m], b[n], acc[m][n], 0, 0, 0); \
        __builtin_amdgcn_s_setprio(0);                             \
    } while (0)

#define S2_PHASE(A_, B_, KN)                                       \
    do {                                                           \
        asm volatile("s_waitcnt vmcnt(8)" ::: "memory");           \
        __builtin_amdgcn_s_barrier();                              \
        MEMFENCE();                                                \
        S2_COMPUTE(A_, B_);                                        \
        __builtin_amdgcn_s_barrier();                              \
        MEMFENCE();                                                \
        S2_STAGE(A_, B_, KN);                                      \
    } while (0)

    const int NT = DHP / 32;       // 44 (== 2 mod 3)
    const int KL = (NT - 1) * 32;
    S2_STAGE(As0, Bs0, 0);
    S2_STAGE(As1, Bs1, 32);
    S2_STAGE(As2, Bs2, 64);

    for (int kt = 0; kt + 4 < NT; kt += 3) {
        S2_PHASE(As0, Bs0, min((kt + 3) * 32, KL));
        S2_PHASE(As1, Bs1, min((kt + 4) * 32, KL));
        S2_PHASE(As2, Bs2, min((kt + 5) * 32, KL));
    }
    asm volatile("s_waitcnt vmcnt(8)" ::: "memory");
    __builtin_amdgcn_s_barrier();
    MEMFENCE();
    S2_COMPUTE(As0, Bs0);
    asm volatile("s_waitcnt vmcnt(4)" ::: "memory");
    __builtin_amdgcn_s_barrier();
    MEMFENCE();
    S2_COMPUTE(As1, Bs1);
    asm volatile("s_waitcnt vmcnt(0)" ::: "memory");
#undef S2_STAGE
#undef S2_COMPUTE
#undef S2_PHASE

    int rmax = ce - rows0;
#pragma unroll
    for (int m = 0; m < 4; ++m) {
#pragma unroll
        for (int r = 0; r < 4; ++r) {
            int rl = wm * 64 + m * 16 + (lane >> 4) * 4 + r;
            if (rl >= rmax) continue;
            int t = tok[oe + rows0 + rl];
            float* yr = y + (size_t)t * DO + o0 + wn * 64 + (lane & 15);
#pragma unroll
            for (int n = 0; n < 4; ++n)
                unsafeAtomicAdd(yr + n * 16, acc[m][n][r]);
        }
    }
}

// ---------------- host launch ----------------
extern "C" void kernel_launch(void* const* d_in, const int* in_sizes, int n_in,
                              void* d_out, int out_size, void* d_ws, size_t ws_size,
                              hipStream_t stream)
{
    const float* x  = (const float*)d_in[0];
    const float* gw = (const float*)d_in[1];
    const float* wg = (const float*)d_in[2];
    const float* bg = (const float*)d_in[3];
    const float* wu = (const float*)d_in[4];
    const float* bu = (const float*)d_in[5];
    const float* wd = (const float*)d_in[6];
    const float* bd = (const float*)d_in[7];
    float* y = (float*)d_out;
    float* loss = y + (size_t)TN * DO;

    uint8_t* ws = (uint8_t*)d_ws;
    u16*   x16   = (u16*)(ws + 0);             // 33,554,432
    u16*   inter = (u16*)(ws + 33554432ull);   // 23,068,672 (stride DHP)
    u16*   wg16  = (u16*)(ws + 56623104ull);   // 90,177,536
    u16*   wu16  = (u16*)(ws + 146800640ull);  // 90,177,536
    u16*   wd16  = (u16*)(ws + 236978176ull);  // 92,274,688 (stride DHP, pad zeroed)
    int*   tok   = (int*)(ws + 329252864ull);
    float* sc    = (float*)(ws + 329285632ull);
    int*   tke   = (int*)(ws + 329318400ull);
    float* tks   = (float*)(ws + 329351168ull);
    int*   misc  = (int*)(ws + 329383936ull);
    int* cnt = misc; int* fill = misc + 8; int* off = misc + 16;
    float* imp = (float*)(misc + 24);

    hipMemsetAsync(misc, 0, 128, stream);
    k_cvt<<<22016, 256, 0, stream>>>(wg, wg16, 5636096);
    k_cvt<<<22016, 256, 0, stream>>>(wu, wu16, 5636096);
    k_cvt_wd<<<22528, 256, 0, stream>>>(wd, wd16);
    k_gate<<<TN, 256, 0, stream>>>(x, gw, x16, tke, tks, cnt, imp);
    k_finalize<<<1, 64, 0, stream>>>(cnt, imp, off, loss);
    k_scatter<<<TN / 256, 256, 0, stream>>>(tke, tks, off, fill, tok, sc);
    k_yinit<<<TN, 256, 0, stream>>>(tke, tks, bd, y);
    k_stage1g<<<dim3(256, 11), 256, 0, stream>>>(x16, wg16, wu16, bg, bu, cnt, off, tok, sc, inter);
    k_stage2g<<<dim3(256, 32), 256, 0, stream>>>(inter, wd16, cnt, off, tok, y);
}